// Round 13
// baseline (1279.031 us; speedup 1.0000x reference)
//
#include <hip/hip_runtime.h>
#include <hip/hip_bf16.h>
#include <math.h>

#define NPOS 8192
#define MAXIT 50
#define TOLF 1e-3f           // effective stop: |f - f_50| ~ gap << 0.0425 budget
#define PADJ 2560            // window [i0-2560, i0+2560); min one-sided radius 2528
#define EUW  13312           // ushorts per plane: 8192 + 2*2560
#define EUSZ (EUW * 8)       // ushorts per eu buffer (8 planes [b][j'])

// ws layout (float offsets)
#define OFF_W2   0           // 16384: w2[d+8191] = exp(K(|d|))
#define OFF_LA   16384       // 65536: log(alpha)
#define OFF_F    81920       // 65536: potential f
#define OFF_CB   147456      // 8: fixed per-batch stabilizer cb = max(la)
#define OFF_SLOT 147464      // 800 uints: gap slots
#define OFF_EU   148480      // 2 * 106496 ushorts (bf16 double buffer) = 106496 floats
#define OFF_VBUF 254976      // 65536 floats: per-tile v accumulators [tile][b][ii]
#define OFF_TICK 320512      // 256 uints: per-tile completion tickets

#define SLOT_DMAX 0          // 50*8
#define SLOT_DMIN 400        // 50*8

__device__ inline unsigned fkey(float x) {
  unsigned b = __float_as_uint(x);
  return (b & 0x80000000u) ? ~b : (b | 0x80000000u);
}
__device__ inline float fval(unsigned k) {
  unsigned b = (k & 0x80000000u) ? (k ^ 0x80000000u) : ~k;
  return __uint_as_float(b);
}

// run body k iff gap_{k-1} >= TOLF (never-run slots -> -inf -> stay stopped)
__device__ inline bool run_iter(const unsigned* slots, int k) {
  if (k == 0) return true;
  const unsigned* dmax = slots + SLOT_DMAX + (k - 1) * 8;
  const unsigned* dmin = slots + SLOT_DMIN + (k - 1) * 8;
  float s = 0.f;
#pragma unroll
  for (int b = 0; b < 8; ++b) s += fval(dmax[b]) - fval(dmin[b]);
  return (s * 0.125f) >= TOLF;
}

// bf16(u16)->f32 via bit ops on packed uint
#define BFLO(u) __uint_as_float((u) << 16)
#define BFHI(u) __uint_as_float((u) & 0xffff0000u)

__global__ __launch_bounds__(256) void setup_a(const float* __restrict__ alpha,
                                               const float* __restrict__ kern,
                                               float* __restrict__ ws) {
  int id = blockIdx.x * 256 + threadIdx.x;        // grid 416 -> 106496 threads
  ((unsigned*)(ws + OFF_EU))[id] = 0u;            // zero both bf16 eu buffers
  if (id < 65536) {
    float a = alpha[id];
    ws[OFF_LA + id] = (a > 0.f) ? logf(a) : -INFINITY;
    ws[OFF_F + id] = 0.f;
    ws[OFF_VBUF + id] = 0.f;                      // zero v accumulators
  }
  if (id < 16384) {
    int d = id - 8191; if (d < 0) d = -d; if (d > 8191) d = 8191;
    ws[OFF_W2 + id] = expf(kern[d]);              // kernel row 0; Toeplitz-exact
  }
  unsigned* slots = (unsigned*)(ws + OFF_SLOT);
  if (id < 400) {
    slots[SLOT_DMAX + id] = fkey(-INFINITY);
    slots[SLOT_DMIN + id] = fkey(INFINITY);
  }
  if (id < 256) ((unsigned*)(ws + OFF_TICK))[id] = 0u;
}

__global__ __launch_bounds__(256) void setup_cb(float* __restrict__ ws) {
  int b = blockIdx.x;
  const float* lap = ws + OFF_LA + b * NPOS;
  float m = -INFINITY;
  for (int i = threadIdx.x; i < NPOS; i += 256) m = fmaxf(m, lap[i]);
#pragma unroll
  for (int o = 1; o < 64; o <<= 1) m = fmaxf(m, __shfl_xor(m, o, 64));
  __shared__ float r[4];
  if ((threadIdx.x & 63) == 0) r[threadIdx.x >> 6] = m;
  __syncthreads();
  if (threadIdx.x == 0)
    ws[OFF_CB + b] = fmaxf(fmaxf(r[0], r[1]), fmaxf(r[2], r[3]));
}

__global__ __launch_bounds__(256) void setup_eu(float* __restrict__ ws) {
  int id = blockIdx.x * 256 + threadIdx.x;        // grid 256 -> 65536
  int b = id >> 13, i = id & (NPOS - 1);
  float la = ws[OFF_LA + id];
  float cb = ws[OFF_CB + b];
  __hip_bfloat16 h = __float2bfloat16(expf(la - cb));
  ((unsigned short*)(ws + OFF_EU))[(size_t)b * EUW + i + PADJ] = *(unsigned short*)&h;
}

// ---- fused iteration: grid 512 (2 blocks/CU -> 4 waves/SIMD) ----
// tile = bid>>1 (i-tile of 32), jc = bid&1 (half-window of 2560 j).
// 8 waves = 8 planes. Lane owns 8 consecutive j per 512-j superstep (5 steps).
// A[32] regs; 5-round halving reduce + cross-half; fp32 atomicAdd into vbuf;
// per-tile ticket: second-finishing block runs fused epilogue + resets.
__global__ __launch_bounds__(512, 4) void iter_k(
    const float* __restrict__ w2, const float* __restrict__ la,
    float* __restrict__ f, const float* __restrict__ cb,
    unsigned* __restrict__ slots, const unsigned short* __restrict__ eu,
    unsigned short* __restrict__ eunext, float* __restrict__ vbuf,
    unsigned* __restrict__ ticket, int k)
{
  if (!run_iter(slots, k)) return;
  const int tile = blockIdx.x >> 1;
  const int jc   = blockIdx.x & 1;
  const int i0   = tile << 5;
  const int t = threadIdx.x;
  const int lane = t & 63;
  const int b = t >> 6;                // wave = plane

  float A[32];
#pragma unroll
  for (int a = 0; a < 32; ++a) A[a] = 0.f;

  // eu (ushort) index: j' = i0 + 2560 jc + 512 s + 8 lane
  const unsigned short* eup = eu + (size_t)b * EUW + (i0 + 2560 * jc + (lane << 3));
  // w2 idx(ii,jj;s) = Bt + ii - jj, Bt = 10751 - 2560 jc - 512 s - 8 lane;
  // Wf[p] = w2[Bt-7+p], wv = Wf[7+ii-jj]; (Bt-7)/4 = 2686 - 640 jc - 128 s - 2 lane.
  const int wq0 = 2686 - 640 * jc - (lane << 1);
  const float4* wp4 = (const float4*)w2;

#pragma unroll
  for (int s = 0; s < 5; ++s) {
    uint4 U = *(const uint4*)(eup + (s << 9));
    float Wf[40];
    {
      const float4* wrow = wp4 + (wq0 - (s << 7));
#pragma unroll
      for (int q = 0; q < 10; ++q) {
        float4 v = wrow[q];
        Wf[4*q] = v.x; Wf[4*q+1] = v.y; Wf[4*q+2] = v.z; Wf[4*q+3] = v.w;
      }
    }
    float e[8];
    e[0]=BFLO(U.x); e[1]=BFHI(U.x); e[2]=BFLO(U.y); e[3]=BFHI(U.y);
    e[4]=BFLO(U.z); e[5]=BFHI(U.z); e[6]=BFLO(U.w); e[7]=BFHI(U.w);
#pragma unroll
    for (int jj = 0; jj < 8; ++jj) {
#pragma unroll
      for (int ii = 0; ii < 32; ++ii)
        A[ii] = fmaf(Wf[7 + ii - jj], e[jj], A[ii]);  // static index after unroll
    }
  }

  // 5-round register-halving reduce within 32-lane halves, then cross-half:
  // lanes L and L+32 end with the full 64-lane sum of original A[L] (L<32).
#pragma unroll
  for (int r = 0; r < 5; ++r) {
    const int bit = (lane >> r) & 1;
#pragma unroll
    for (int m = 0; m < (16 >> r); ++m) {
      float x = bit ? A[2 * m + 1] : A[2 * m];
      A[m] = x + __shfl_xor(x, 1 << r, 64);
    }
  }
  A[0] += __shfl_xor(A[0], 32, 64);

  if (lane < 32) atomicAdd(&vbuf[(tile << 8) + (b << 5) + lane], A[0]);

  // ---- per-tile completion ticket; second finisher runs the epilogue ----
  __threadfence();                     // release vbuf adds
  __syncthreads();                     // all waves' adds issued+fenced
  __shared__ unsigned oldt;
  if (t == 0) oldt = atomicAdd(&ticket[tile], 1u);
  __syncthreads();
  if (oldt != 1) return;               // first finisher exits
  __threadfence();                     // acquire both blocks' adds

  if (t < 256) {
    const int bb = t >> 5;
    const int ii = t & 31;
    const int i = i0 + ii;
    float v = vbuf[(tile << 8) + t];
    vbuf[(tile << 8) + t] = 0.f;       // reset for next dispatch
    const float cbb = cb[bb];
    float g = -2.f * (logf(v) + cbb);
    float* fp = f + (size_t)bb * NPOS + i;
    float fo = *fp;
    float d  = fo - g;
    float fn = 0.5f * (fo + g);
    *fp = fn;
    float un = 0.5f * fn + la[(size_t)bb * NPOS + i];
    __hip_bfloat16 h = __float2bfloat16(expf(un - cbb));
    eunext[(size_t)bb * EUW + i + PADJ] = *(unsigned short*)&h;
    float dmax = d, dmin = d;
#pragma unroll
    for (int o = 1; o < 32; o <<= 1) { // reduce over this plane's 32 i
      dmax = fmaxf(dmax, __shfl_xor(dmax, o, 64));
      dmin = fminf(dmin, __shfl_xor(dmin, o, 64));
    }
    if ((t & 31) == 0) {
      atomicMax(&slots[SLOT_DMAX + k * 8 + bb], fkey(dmax));
      atomicMin(&slots[SLOT_DMIN + k * 8 + bb], fkey(dmin));
    }
  }
  if (t == 0) ticket[tile] = 0u;       // reset ticket for next dispatch
}

__global__ __launch_bounds__(256) void value_k(const float* __restrict__ alpha,
                                               const float* __restrict__ ws,
                                               float* __restrict__ out) {
  int b = blockIdx.x;
  const float* fp = ws + OFF_F + b * NPOS;
  const float* ap = alpha + b * NPOS;
  float s = 0.f;
  for (int i = threadIdx.x; i < NPOS; i += 256) s = fmaf(fp[i], ap[i], s);
#pragma unroll
  for (int o = 1; o < 64; o <<= 1) s += __shfl_xor(s, o, 64);
  __shared__ float red[4];
  if ((threadIdx.x & 63) == 0) red[threadIdx.x >> 6] = s;
  __syncthreads();
  if (threadIdx.x == 0) out[b] = -(red[0] + red[1] + red[2] + red[3]);
}

extern "C" void kernel_launch(void* const* d_in, const int* in_sizes, int n_in,
                              void* d_out, int out_size, void* d_ws, size_t ws_size,
                              hipStream_t stream) {
  const float* alpha = (const float*)d_in[0];
  const float* kern  = (const float*)d_in[1];
  float* ws  = (float*)d_ws;
  float* out = (float*)d_out;

  float* w2p = ws + OFF_W2;
  float* lap = ws + OFF_LA;
  float* fp  = ws + OFF_F;
  float* cbp = ws + OFF_CB;
  unsigned* slots = (unsigned*)(ws + OFF_SLOT);
  unsigned short* eub = (unsigned short*)(ws + OFF_EU);
  float* vbufp = ws + OFF_VBUF;
  unsigned* tickp = (unsigned*)(ws + OFF_TICK);

  setup_a<<<416, 256, 0, stream>>>(alpha, kern, ws);
  setup_cb<<<8, 256, 0, stream>>>(ws);
  setup_eu<<<256, 256, 0, stream>>>(ws);
  for (int k = 0; k < MAXIT; ++k) {
    unsigned short* ecur = eub + (size_t)(k & 1) * EUSZ;
    unsigned short* enxt = eub + (size_t)((k + 1) & 1) * EUSZ;
    iter_k<<<512, 512, 0, stream>>>(w2p, lap, fp, cbp, slots, ecur, enxt,
                                    vbufp, tickp, k);
  }
  value_k<<<8, 256, 0, stream>>>(alpha, ws, out);
}

// Round 14
// 299.886 us; speedup vs baseline: 4.2651x; 4.2651x over previous
//
#include <hip/hip_runtime.h>
#include <math.h>

#define NPOS 8192
#define MAXIT 50
#define TOLF 2e-3f           // fp32 eu noise floor ~1e-6 << TOLF; f-err ~ 8e-3 << budget
#define PADJ 2560            // window [i0-2560, i0+2560); min one-sided radius 2528
#define EUW  13312           // floats per plane: 8192 + 2*2560
#define EUSZ (EUW * 8)       // floats per eu buffer (8 planes [b][j'])

// ws layout (float offsets)
#define OFF_W2   0           // 16384: w2[d+8191] = exp(K(|d|))
#define OFF_LA   16384       // 65536: log(alpha)
#define OFF_F    81920       // 65536: potential f
#define OFF_CB   147456      // 8: fixed per-batch stabilizer cb = max(la)
#define OFF_SLOT 147464      // 800 uints: gap slots
#define OFF_EU   148480      // 2 * 106496 floats (fp32 double buffer)

#define SLOT_DMAX 0          // 50*8
#define SLOT_DMIN 400        // 50*8

// static float4 component select (folds at compile time under #pragma unroll)
#define EC(v,kk) ((kk)==0?(v).x:(kk)==1?(v).y:(kk)==2?(v).z:(v).w)

__device__ inline unsigned fkey(float x) {
  unsigned b = __float_as_uint(x);
  return (b & 0x80000000u) ? ~b : (b | 0x80000000u);
}
__device__ inline float fval(unsigned k) {
  unsigned b = (k & 0x80000000u) ? (k ^ 0x80000000u) : ~k;
  return __uint_as_float(b);
}

// run body k iff gap_{k-1} >= TOLF (never-run slots -> -inf -> stay stopped)
__device__ inline bool run_iter(const unsigned* slots, int k) {
  if (k == 0) return true;
  const unsigned* dmax = slots + SLOT_DMAX + (k - 1) * 8;
  const unsigned* dmin = slots + SLOT_DMIN + (k - 1) * 8;
  float s = 0.f;
#pragma unroll
  for (int b = 0; b < 8; ++b) s += fval(dmax[b]) - fval(dmin[b]);
  return (s * 0.125f) >= TOLF;
}

__global__ __launch_bounds__(256) void setup_a(const float* __restrict__ alpha,
                                               const float* __restrict__ kern,
                                               float* __restrict__ ws) {
  int id = blockIdx.x * 256 + threadIdx.x;        // grid 832 -> 212992 threads
  ws[OFF_EU + id] = 0.f;                          // zero both eu buffers (2*106496)
  if (id < 16384) {
    int d = id - 8191; if (d < 0) d = -d; if (d > 8191) d = 8191;
    ws[OFF_W2 + id] = expf(kern[d]);              // kernel row 0; Toeplitz-exact
  }
  if (id < 65536) {
    float a = alpha[id];
    ws[OFF_LA + id] = (a > 0.f) ? logf(a) : -INFINITY;
    ws[OFF_F + id] = 0.f;
  }
  unsigned* slots = (unsigned*)(ws + OFF_SLOT);
  if (id < 400) {
    slots[SLOT_DMAX + id] = fkey(-INFINITY);
    slots[SLOT_DMIN + id] = fkey(INFINITY);
  }
}

__global__ __launch_bounds__(256) void setup_cb(float* __restrict__ ws) {
  int b = blockIdx.x;
  const float* lap = ws + OFF_LA + b * NPOS;
  float m = -INFINITY;
  for (int i = threadIdx.x; i < NPOS; i += 256) m = fmaxf(m, lap[i]);
#pragma unroll
  for (int o = 1; o < 64; o <<= 1) m = fmaxf(m, __shfl_xor(m, o, 64));
  __shared__ float r[4];
  if ((threadIdx.x & 63) == 0) r[threadIdx.x >> 6] = m;
  __syncthreads();
  if (threadIdx.x == 0)
    ws[OFF_CB + b] = fmaxf(fmaxf(r[0], r[1]), fmaxf(r[2], r[3]));
}

__global__ __launch_bounds__(256) void setup_eu(float* __restrict__ ws) {
  int id = blockIdx.x * 256 + threadIdx.x;        // grid 256 -> 65536
  int b = id >> 13, i = id & (NPOS - 1);
  float la = ws[OFF_LA + id];
  float cb = ws[OFF_CB + b];
  ws[OFF_EU + (size_t)b * EUW + i + PADJ] = expf(la - cb);
}

// ---- fused iteration (r10 geometry, fp32 eu): grid 256, 512 thr = 8 waves ----
// i-tile 32; 8 waves = 4 plane-pairs (pg) x 2 j-chunks (jc, 2560 j).
// Lane owns 8 consecutive j per 512-j superstep (5 supersteps).
// Per superstep: 10 w float4 + 4 eu float4 per 512 FMAs.
// A[64]; 6-round register-halving reduce; LDS combine; fused epilogue.
__global__ __launch_bounds__(512, 2) void iter_k(
    const float* __restrict__ w2, const float* __restrict__ la,
    float* __restrict__ f, const float* __restrict__ cb,
    unsigned* __restrict__ slots, const float* __restrict__ eu,
    float* __restrict__ eunext, int k)
{
  if (!run_iter(slots, k)) return;
  const int i0 = blockIdx.x << 5;      // grid 256
  const int t = threadIdx.x;
  const int lane = t & 63;
  const int wid  = t >> 6;
  const int pg = wid & 3;              // plane-pair: planes 2pg, 2pg+1
  const int jc = wid >> 2;             // j-chunk half

  float A[64];
#pragma unroll
  for (int a = 0; a < 64; ++a) A[a] = 0.f;

  // eu (float) index: j' = i0 + 2560 jc + 512 s + 8 lane (+jj)
  const float* eup = eu + (size_t)(2 * pg) * EUW + (i0 + 2560 * jc + (lane << 3));
  // w2 idx(ii,jj;s) = Bt + ii - jj, Bt = 10751 - 2560 jc - 512 s - 8 lane;
  // Wf[p] = w2[Bt-7+p], wv = Wf[7+ii-jj]; (Bt-7)/4 = 2686 - 640 jc - 128 s - 2 lane.
  const int wq0 = 2686 - 640 * jc - (lane << 1);
  const float4* wp4 = (const float4*)w2;

#pragma unroll
  for (int s = 0; s < 5; ++s) {
    float4 E0a = *(const float4*)(eup + (s << 9));
    float4 E0b = *(const float4*)(eup + (s << 9) + 4);
    float4 E1a = *(const float4*)(eup + EUW + (s << 9));
    float4 E1b = *(const float4*)(eup + EUW + (s << 9) + 4);
    float Wf[40];
    {
      const float4* wrow = wp4 + (wq0 - (s << 7));
#pragma unroll
      for (int q = 0; q < 10; ++q) {
        float4 v = wrow[q];
        Wf[4*q] = v.x; Wf[4*q+1] = v.y; Wf[4*q+2] = v.z; Wf[4*q+3] = v.w;
      }
    }
#pragma unroll
    for (int jj = 0; jj < 8; ++jj) {
      const float e0 = (jj < 4) ? EC(E0a, jj) : EC(E0b, jj - 4);
      const float e1 = (jj < 4) ? EC(E1a, jj) : EC(E1b, jj - 4);
#pragma unroll
      for (int ii = 0; ii < 32; ++ii) {
        const float wv = Wf[7 + ii - jj];         // static index after unroll
        A[ii]      = fmaf(wv, e0, A[ii]);
        A[32 + ii] = fmaf(wv, e1, A[32 + ii]);
      }
    }
  }

  // register-halving cross-lane reduce: lane L ends with wave-sum of A[L]
#pragma unroll
  for (int r = 0; r < 6; ++r) {
    const int bit = (lane >> r) & 1;
#pragma unroll
    for (int m = 0; m < (32 >> r); ++m) {
      float x = bit ? A[2 * m + 1] : A[2 * m];
      A[m] = x + __shfl_xor(x, 1 << r, 64);
    }
  }
  __shared__ float smem[8][64];
  smem[wid][lane] = A[0];
  __syncthreads();

  if (t < 256) {                       // wave pg2 handles planes 2pg2, 2pg2+1
    const int pg2 = t >> 6, L = t & 63;
    float v = smem[pg2][L] + smem[pg2 + 4][L];    // combine the two j-chunks
    const int b = 2 * pg2 + (L >> 5);
    const int i = i0 + (L & 31);
    const float cbb = cb[b];
    float g = -2.f * (logf(v) + cbb);
    float* fp = f + (size_t)b * NPOS + i;
    float fo = *fp;
    float d  = fo - g;
    float fn = 0.5f * (fo + g);
    *fp = fn;
    float un = 0.5f * fn + la[(size_t)b * NPOS + i];
    eunext[(size_t)b * EUW + i + PADJ] = expf(un - cbb);
    float dmax = d, dmin = d;
#pragma unroll
    for (int o = 1; o < 32; o <<= 1) {            // reduce over this plane's 32 i
      dmax = fmaxf(dmax, __shfl_xor(dmax, o, 64));
      dmin = fminf(dmin, __shfl_xor(dmin, o, 64));
    }
    if ((L & 31) == 0) {
      atomicMax(&slots[SLOT_DMAX + k * 8 + b], fkey(dmax));
      atomicMin(&slots[SLOT_DMIN + k * 8 + b], fkey(dmin));
    }
  }
}

__global__ __launch_bounds__(256) void value_k(const float* __restrict__ alpha,
                                               const float* __restrict__ ws,
                                               float* __restrict__ out) {
  int b = blockIdx.x;
  const float* fp = ws + OFF_F + b * NPOS;
  const float* ap = alpha + b * NPOS;
  float s = 0.f;
  for (int i = threadIdx.x; i < NPOS; i += 256) s = fmaf(fp[i], ap[i], s);
#pragma unroll
  for (int o = 1; o < 64; o <<= 1) s += __shfl_xor(s, o, 64);
  __shared__ float red[4];
  if ((threadIdx.x & 63) == 0) red[threadIdx.x >> 6] = s;
  __syncthreads();
  if (threadIdx.x == 0) out[b] = -(red[0] + red[1] + red[2] + red[3]);
}

extern "C" void kernel_launch(void* const* d_in, const int* in_sizes, int n_in,
                              void* d_out, int out_size, void* d_ws, size_t ws_size,
                              hipStream_t stream) {
  const float* alpha = (const float*)d_in[0];
  const float* kern  = (const float*)d_in[1];
  float* ws  = (float*)d_ws;
  float* out = (float*)d_out;

  float* w2p = ws + OFF_W2;
  float* lap = ws + OFF_LA;
  float* fp  = ws + OFF_F;
  float* cbp = ws + OFF_CB;
  unsigned* slots = (unsigned*)(ws + OFF_SLOT);
  float* eub = ws + OFF_EU;

  setup_a<<<832, 256, 0, stream>>>(alpha, kern, ws);
  setup_cb<<<8, 256, 0, stream>>>(ws);
  setup_eu<<<256, 256, 0, stream>>>(ws);
  for (int k = 0; k < MAXIT; ++k) {
    float* ecur = eub + (size_t)(k & 1) * EUSZ;
    float* enxt = eub + (size_t)((k + 1) & 1) * EUSZ;
    iter_k<<<256, 512, 0, stream>>>(w2p, lap, fp, cbp, slots, ecur, enxt, k);
  }
  value_k<<<8, 256, 0, stream>>>(alpha, ws, out);
}